// Round 5
// baseline (93.443 us; speedup 1.0000x reference)
//
#include <hip/hip_runtime.h>
#include <math.h>

// TropConv2D: out[b,i,j,f] = max_k(p[k]+w[k,f]) - min_k(p[k]+w[k,f]) + bias[f]
// k = (ki*3+kj)*32+c, 3x3 window, C=32, F=64.
// x: [8,32,32,32] f32, w: [288,64] f32, bias: [64] f32, out: [8,30,30,64] f32.
//
// R5: packed-f16 taps (v_pk_add/max/min_f16, 2 channel-taps per inst ->
// 1.5 insts/tap vs 2.33 f32). Error budget: f16 rounding ~0.01 << 0.17375
// threshold. w staged ONCE transposed in LDS as f16 wt[f][288] (37.9 KB,
// stride 148 words -> start banks uniform, min-phase b128 reads). x rows
// converted once to f16 in LDS (6 KB), read via wave-uniform broadcast b128.
// Exactly one __syncthreads in the whole kernel (was 6 in R4).

typedef _Float16 half2v __attribute__((ext_vector_type(2)));
typedef _Float16 half8v __attribute__((ext_vector_type(8)));

#define WSTRIDE 296  // halves; 148 words, %32=20 (gcd 4) -> uniform bank starts

__global__ __launch_bounds__(512) void trop_kernel(
    const float* __restrict__ x, const float* __restrict__ w,
    const float* __restrict__ bias, float* __restrict__ out) {
  __shared__ _Float16 wt[64 * WSTRIDE];  // 37.9 KB: w transposed [f][kk]
  __shared__ _Float16 xh[3 * 32 * 32];   // 6 KB: x rows f16 [ki][col][c]

  const int i = blockIdx.x;  // 0..29 output row
  const int b = blockIdx.y;  // 0..7 batch
  const int tid = threadIdx.x;
  const int f = tid & 63;  // lane = filter
  // wave-uniform column base: waves 0..7 -> cols 0,4,...,28 (wave 7: 2 valid)
  const int j0 = __builtin_amdgcn_readfirstlane(tid >> 6) * 4;

  // ---- stage w transposed + f16: 72 k-quads per f-column, 8 workers/f ----
  const int skq = tid >> 6;  // 0..7 quad-worker
#pragma unroll
  for (int it = 0; it < 9; ++it) {
    int k0 = (it * 8 + skq) * 4;  // 0..284 step 4
    const float* wp = w + (size_t)k0 * 64 + f;
    _Float16 h0 = (_Float16)wp[0 * 64];
    _Float16 h1 = (_Float16)wp[1 * 64];
    _Float16 h2 = (_Float16)wp[2 * 64];
    _Float16 h3 = (_Float16)wp[3 * 64];
    half2v* dst = (half2v*)&wt[f * WSTRIDE + k0];
    dst[0] = half2v{h0, h1};  // 8B ds_write
    dst[1] = half2v{h2, h3};
  }

  // ---- stage x rows i..i+2 as f16: 1536 float2 loads, 3 per thread ----
  const float* xb = x + (((size_t)b * 32 + i) * 32) * 32;
#pragma unroll
  for (int t = 0; t < 3; ++t) {
    int g = tid + t * 512;        // 0..1535 = (ki, col, cpair)
    int ki = g >> 9;              // /512
    int rem = g & 511;
    int col = rem >> 4;           // 0..31
    int cp = rem & 15;            // channel pair
    float2 v = *(const float2*)(xb + ki * 1024 + col * 32 + cp * 2);
    *(half2v*)&xh[(ki * 32 + col) * 32 + cp * 2] =
        half2v{(_Float16)v.x, (_Float16)v.y};
  }

  __syncthreads();  // the only barrier

  half2v mxp[4], mnp[4];
  const _Float16 NI = (_Float16)(-INFINITY), PI = (_Float16)INFINITY;
#pragma unroll
  for (int p = 0; p < 4; ++p) {
    mxp[p] = half2v{NI, NI};
    mnp[p] = half2v{PI, PI};
  }

#pragma unroll
  for (int ki = 0; ki < 3; ++ki) {
#pragma unroll
    for (int c8 = 0; c8 < 32; c8 += 8) {
      // x: 6 cols x 8 ch, wave-uniform broadcast b128 reads
      half2v xv[6][4];
#pragma unroll
      for (int col = 0; col < 6; ++col) {
        int cc = (j0 + col < 32) ? j0 + col : 31;  // clamp at image edge
        half8v hv = *(const half8v*)&xh[(ki * 32 + cc) * 32 + c8];
#pragma unroll
        for (int q = 0; q < 4; ++q) xv[col][q] = half2v{hv[2 * q], hv[2 * q + 1]};
      }
      // w: lane f's own row, 3 kj x 8 ch via b128 (uniform bank starts)
      half2v wv[3][4];
#pragma unroll
      for (int kj = 0; kj < 3; ++kj) {
        half8v hv = *(const half8v*)&wt[f * WSTRIDE + ki * 96 + kj * 32 + c8];
#pragma unroll
        for (int q = 0; q < 4; ++q) wv[kj][q] = half2v{hv[2 * q], hv[2 * q + 1]};
      }
      // packed taps: 2 channels per instruction
#pragma unroll
      for (int q = 0; q < 4; ++q) {
#pragma unroll
        for (int kj = 0; kj < 3; ++kj) {
          half2v wq = wv[kj][q];
#pragma unroll
          for (int p = 0; p < 4; ++p) {
            half2v a = xv[p + kj][q] + wq;                    // v_pk_add_f16
            mxp[p] = __builtin_elementwise_max(mxp[p], a);    // v_pk_max_f16
            mnp[p] = __builtin_elementwise_min(mnp[p], a);    // v_pk_min_f16
          }
        }
      }
    }
  }

  // ---- epilogue: f32 subtract + bias; coalesced 256 B stores ----
  float bv = bias[f];
  float* ob = out + (((size_t)b * 30 + i) * 30 + j0) * 64 + f;
#pragma unroll
  for (int p = 0; p < 4; ++p) {
    if (j0 + p < 30) {
      float m = fmaxf((float)mxp[p].x, (float)mxp[p].y);
      float n = fminf((float)mnp[p].x, (float)mnp[p].y);
      ob[(size_t)p * 64] = m - n + bv;
    }
  }
}

extern "C" void kernel_launch(void* const* d_in, const int* in_sizes, int n_in,
                              void* d_out, int out_size, void* d_ws, size_t ws_size,
                              hipStream_t stream) {
  const float* x = (const float*)d_in[0];
  const float* w = (const float*)d_in[1];
  const float* bias = (const float*)d_in[2];
  float* out = (float*)d_out;
  dim3 grid(30, 8);  // (row, batch) = 240 blocks, 8 waves each
  dim3 block(512);
  hipLaunchKernelGGL(trop_kernel, grid, block, 0, stream, x, w, bias, out);
}

// Round 6
// 91.784 us; speedup vs baseline: 1.0181x; 1.0181x over previous
//
#include <hip/hip_runtime.h>
#include <math.h>

// TropConv2D: out[b,i,j,f] = max_k(p[k]+w[k,f]) - min_k(p[k]+w[k,f]) + bias[f]
// k = (ki*3+kj)*32+c, 3x3 window, C=32, F=64.
// x: [8,32,32,32] f32, w: [288,64] f32, bias: [64] f32, out: [8,30,30,64] f32.
//
// R6: packed-f16 taps (1.5 insts/tap), SCRATCH-PROOF codegen: no arrays, no
// variable vector indexing (R5's spill cause: 65 MB scratch writes, VALUBusy
// 0.1%). LDS reads as uint4, dwords extracted via named fields + bit_cast.
// w staged once transposed f16 wt[f][288] (stride 296 halves: b128 row reads
// hit each bank exactly 8x = minimum phases). x staged once f16 (6 KB),
// wave-uniform broadcast b128 reads. One __syncthreads total.
// f16 error ~0.06 measured (R5) vs 0.174 threshold.

typedef _Float16 half2v __attribute__((ext_vector_type(2)));
typedef _Float16 half4v __attribute__((ext_vector_type(4)));

#define WSTRIDE 296  // halves; 148 words %32=20 -> 8 uniform start banks

__device__ __forceinline__ void tap(half2v a, half2v& mx, half2v& mn) {
  mx = __builtin_elementwise_max(mx, a);  // v_pk_max_f16
  mn = __builtin_elementwise_min(mn, a);  // v_pk_min_f16
}

__global__ __launch_bounds__(512) void trop_kernel(
    const float* __restrict__ x, const float* __restrict__ w,
    const float* __restrict__ bias, float* __restrict__ out) {
  __shared__ _Float16 wt[64 * WSTRIDE];  // 37.9 KB: w transposed [f][kk], f16
  __shared__ _Float16 xh[3 * 32 * 32];   // 6 KB: x rows f16 [ki][col][c]

  const int i = blockIdx.x;  // 0..29 output row
  const int b = blockIdx.y;  // 0..7 batch
  const int tid = threadIdx.x;
  const int f = tid & 63;  // lane = filter
  const int j0 = __builtin_amdgcn_readfirstlane(tid >> 6) * 4;  // wave col base

  // ---- stage w transposed + f16: lanes f coalesced, 9 quads per thread ----
  const int skq = tid >> 6;  // 0..7
#pragma unroll
  for (int it = 0; it < 9; ++it) {
    int k0 = (it * 8 + skq) * 4;  // 0..284 step 4
    const float* wp = w + (size_t)k0 * 64 + f;
    half4v hv;
    hv.x = (_Float16)wp[0 * 64];
    hv.y = (_Float16)wp[1 * 64];
    hv.z = (_Float16)wp[2 * 64];
    hv.w = (_Float16)wp[3 * 64];
    *(half4v*)&wt[f * WSTRIDE + k0] = hv;  // 8 B aligned ds_write
  }

  // ---- stage x rows i..i+2 as f16: 1536 float2 loads, 3 per thread ----
  const float* xb = x + (((size_t)b * 32 + i) * 32) * 32;
#pragma unroll
  for (int t = 0; t < 3; ++t) {
    int g = tid + t * 512;  // (ki, col, cpair)
    int ki = g >> 9;
    int rem = g & 511;
    int col = rem >> 4;
    int cp = rem & 15;
    float2 v = *(const float2*)(xb + ki * 1024 + col * 32 + cp * 2);
    half2v h;
    h.x = (_Float16)v.x;
    h.y = (_Float16)v.y;
    *(half2v*)&xh[(ki * 32 + col) * 32 + cp * 2] = h;
  }

  __syncthreads();  // the only barrier

  // clamped local columns (wave-uniform)
  const int cc0 = (j0 + 0 < 32) ? j0 + 0 : 31;
  const int cc1 = (j0 + 1 < 32) ? j0 + 1 : 31;
  const int cc2 = (j0 + 2 < 32) ? j0 + 2 : 31;
  const int cc3 = (j0 + 3 < 32) ? j0 + 3 : 31;
  const int cc4 = (j0 + 4 < 32) ? j0 + 4 : 31;
  const int cc5 = (j0 + 5 < 32) ? j0 + 5 : 31;

  const _Float16 NI = (_Float16)(-INFINITY), PI = (_Float16)INFINITY;
  half2v mx0 = {NI, NI}, mx1 = {NI, NI}, mx2 = {NI, NI}, mx3 = {NI, NI};
  half2v mn0 = {PI, PI}, mn1 = {PI, PI}, mn2 = {PI, PI}, mn3 = {PI, PI};

#pragma unroll
  for (int ki = 0; ki < 3; ++ki) {
    const _Float16* xrow = &xh[ki * 32 * 32];
    const _Float16* wrow = &wt[f * WSTRIDE + ki * 96];
#pragma unroll
    for (int c8 = 0; c8 < 32; c8 += 8) {
      // x: 6 cols x 8 ch, wave-uniform broadcast b128
      uint4 xa0 = *(const uint4*)&xrow[cc0 * 32 + c8];
      uint4 xa1 = *(const uint4*)&xrow[cc1 * 32 + c8];
      uint4 xa2 = *(const uint4*)&xrow[cc2 * 32 + c8];
      uint4 xa3 = *(const uint4*)&xrow[cc3 * 32 + c8];
      uint4 xa4 = *(const uint4*)&xrow[cc4 * 32 + c8];
      uint4 xa5 = *(const uint4*)&xrow[cc5 * 32 + c8];
      // w: lane f's own row, 3 kj, b128 each
      uint4 wa0 = *(const uint4*)&wrow[0 * 32 + c8];
      uint4 wa1 = *(const uint4*)&wrow[1 * 32 + c8];
      uint4 wa2 = *(const uint4*)&wrow[2 * 32 + c8];

#define DOD(D)                                                       \
  {                                                                  \
    half2v w0 = __builtin_bit_cast(half2v, wa0.D);                   \
    half2v w1 = __builtin_bit_cast(half2v, wa1.D);                   \
    half2v w2 = __builtin_bit_cast(half2v, wa2.D);                   \
    half2v x0 = __builtin_bit_cast(half2v, xa0.D);                   \
    half2v x1 = __builtin_bit_cast(half2v, xa1.D);                   \
    half2v x2 = __builtin_bit_cast(half2v, xa2.D);                   \
    half2v x3 = __builtin_bit_cast(half2v, xa3.D);                   \
    half2v x4 = __builtin_bit_cast(half2v, xa4.D);                   \
    half2v x5 = __builtin_bit_cast(half2v, xa5.D);                   \
    tap(x0 + w0, mx0, mn0); tap(x1 + w0, mx1, mn1);                  \
    tap(x2 + w0, mx2, mn2); tap(x3 + w0, mx3, mn3);                  \
    tap(x1 + w1, mx0, mn0); tap(x2 + w1, mx1, mn1);                  \
    tap(x3 + w1, mx2, mn2); tap(x4 + w1, mx3, mn3);                  \
    tap(x2 + w2, mx0, mn0); tap(x3 + w2, mx1, mn1);                  \
    tap(x4 + w2, mx2, mn2); tap(x5 + w2, mx3, mn3);                  \
  }
      DOD(x) DOD(y) DOD(z) DOD(w)
#undef DOD
    }
  }

  // ---- epilogue: f32 subtract + bias; coalesced 256 B stores ----
  float bv = bias[f];
  float* ob = out + (((size_t)b * 30 + i) * 30 + j0) * 64 + f;
  if (j0 + 0 < 30) ob[0 * 64] = fmaxf((float)mx0.x, (float)mx0.y) - fminf((float)mn0.x, (float)mn0.y) + bv;
  if (j0 + 1 < 30) ob[1 * 64] = fmaxf((float)mx1.x, (float)mx1.y) - fminf((float)mn1.x, (float)mn1.y) + bv;
  if (j0 + 2 < 30) ob[2 * 64] = fmaxf((float)mx2.x, (float)mx2.y) - fminf((float)mn2.x, (float)mn2.y) + bv;
  if (j0 + 3 < 30) ob[3 * 64] = fmaxf((float)mx3.x, (float)mx3.y) - fminf((float)mn3.x, (float)mn3.y) + bv;
}

extern "C" void kernel_launch(void* const* d_in, const int* in_sizes, int n_in,
                              void* d_out, int out_size, void* d_ws, size_t ws_size,
                              hipStream_t stream) {
  const float* x = (const float*)d_in[0];
  const float* w = (const float*)d_in[1];
  const float* bias = (const float*)d_in[2];
  float* out = (float*)d_out;
  dim3 grid(30, 8);  // (row, batch) = 240 blocks, 8 waves each
  dim3 block(512);
  hipLaunchKernelGGL(trop_kernel, grid, block, 0, stream, x, w, bias, out);
}

// Round 7
// 66.710 us; speedup vs baseline: 1.4007x; 1.3759x over previous
//
#include <hip/hip_runtime.h>
#include <math.h>

// TropConv2D: out[b,i,j,f] = max_k(p[k]+w[k,f]) - min_k(p[k]+w[k,f]) + bias[f]
// k = (ki*3+kj)*32+c, 3x3 window, C=32, F=64.
// x: [8,32,32,32] f32, w: [288,64] f32, bias: [64] f32, out: [8,30,30,64] f32.
//
// R7 = R6 (packed-f16 taps, 1.5 insts/tap, one-barrier LDS staging) with the
// k-loop UNROLL DISABLED. R6's remaining 54 MB FETCH / 60 MB WRITE was scratch
// spill caused by full unroll + ds_read clustering (108 independent b128 loads
// hoisted past the 128-VGPR cap). Flat 12-iter loop, unroll(disable): live set
// ~60 VGPRs -> no spill. w transposed f16 wt[f][288] (stride 296 halves,
// 16B-aligned rows, lane reads own row via b128). x f16 in LDS (6 KB),
// wave-uniform broadcast b128 reads. f16 error 0.0625 vs 0.174 threshold.

typedef _Float16 half2v __attribute__((ext_vector_type(2)));
typedef _Float16 half4v __attribute__((ext_vector_type(4)));

#define WSTRIDE 296  // halves; rows 16B-aligned

__device__ __forceinline__ void tap(half2v a, half2v& mx, half2v& mn) {
  mx = __builtin_elementwise_max(mx, a);  // v_pk_max_f16
  mn = __builtin_elementwise_min(mn, a);  // v_pk_min_f16
}

__global__ __launch_bounds__(512) void trop_kernel(
    const float* __restrict__ x, const float* __restrict__ w,
    const float* __restrict__ bias, float* __restrict__ out) {
  __shared__ _Float16 wt[64 * WSTRIDE];  // 37.9 KB: w transposed [f][kk], f16
  __shared__ _Float16 xh[3 * 32 * 32];   // 6 KB: x rows f16 [ki][col][c]

  const int i = blockIdx.x;  // 0..29 output row
  const int b = blockIdx.y;  // 0..7 batch
  const int tid = threadIdx.x;
  const int f = tid & 63;  // lane = filter
  const int j0 = __builtin_amdgcn_readfirstlane(tid >> 6) * 4;  // wave col base

  // ---- stage w transposed + f16: lanes f coalesced, 9 quads per thread ----
  const int skq = tid >> 6;  // 0..7
#pragma unroll
  for (int it = 0; it < 9; ++it) {
    int k0 = (it * 8 + skq) * 4;  // 0..284 step 4
    const float* wp = w + (size_t)k0 * 64 + f;
    half4v hv;
    hv.x = (_Float16)wp[0 * 64];
    hv.y = (_Float16)wp[1 * 64];
    hv.z = (_Float16)wp[2 * 64];
    hv.w = (_Float16)wp[3 * 64];
    *(half4v*)&wt[f * WSTRIDE + k0] = hv;  // 8 B aligned ds_write
  }

  // ---- stage x rows i..i+2 as f16: 1536 float2 loads, 3 per thread ----
  const float* xb = x + (((size_t)b * 32 + i) * 32) * 32;
#pragma unroll
  for (int t = 0; t < 3; ++t) {
    int g = tid + t * 512;  // (ki, col, cpair)
    int ki = g >> 9;
    int rem = g & 511;
    int col = rem >> 4;
    int cp = rem & 15;
    float2 v = *(const float2*)(xb + ki * 1024 + col * 32 + cp * 2);
    half2v h;
    h.x = (_Float16)v.x;
    h.y = (_Float16)v.y;
    *(half2v*)&xh[(ki * 32 + col) * 32 + cp * 2] = h;
  }

  __syncthreads();  // the only barrier

  // clamped local columns (wave-uniform), as byte offsets into a ki-row
  const int cc0 = ((j0 + 0 < 32) ? j0 + 0 : 31) * 32;
  const int cc1 = ((j0 + 1 < 32) ? j0 + 1 : 31) * 32;
  const int cc2 = ((j0 + 2 < 32) ? j0 + 2 : 31) * 32;
  const int cc3 = ((j0 + 3 < 32) ? j0 + 3 : 31) * 32;
  const int cc4 = ((j0 + 4 < 32) ? j0 + 4 : 31) * 32;
  const int cc5 = ((j0 + 5 < 32) ? j0 + 5 : 31) * 32;

  const _Float16 NI = (_Float16)(-INFINITY), PI = (_Float16)INFINITY;
  half2v mx0 = {NI, NI}, mx1 = {NI, NI}, mx2 = {NI, NI}, mx3 = {NI, NI};
  half2v mn0 = {PI, PI}, mn1 = {PI, PI}, mn2 = {PI, PI}, mn3 = {PI, PI};

#pragma clang loop unroll(disable)
  for (int kc = 0; kc < 12; ++kc) {
    const int ki = kc >> 2;         // 0..2
    const int c8 = (kc & 3) << 3;   // 0,8,16,24
    const _Float16* xrow = &xh[ki * 1024 + c8];
    const _Float16* wrow = &wt[f * WSTRIDE + ki * 96 + c8];

    // x: 6 cols x 8 ch, wave-uniform broadcast b128
    uint4 xa0 = *(const uint4*)&xrow[cc0];
    uint4 xa1 = *(const uint4*)&xrow[cc1];
    uint4 xa2 = *(const uint4*)&xrow[cc2];
    uint4 xa3 = *(const uint4*)&xrow[cc3];
    uint4 xa4 = *(const uint4*)&xrow[cc4];
    uint4 xa5 = *(const uint4*)&xrow[cc5];
    // w: lane f's own row, 3 kj, b128 each
    uint4 wa0 = *(const uint4*)&wrow[0];
    uint4 wa1 = *(const uint4*)&wrow[32];
    uint4 wa2 = *(const uint4*)&wrow[64];

#define DOD(D)                                                       \
  {                                                                  \
    half2v w0 = __builtin_bit_cast(half2v, wa0.D);                   \
    half2v w1 = __builtin_bit_cast(half2v, wa1.D);                   \
    half2v w2 = __builtin_bit_cast(half2v, wa2.D);                   \
    half2v x0 = __builtin_bit_cast(half2v, xa0.D);                   \
    half2v x1 = __builtin_bit_cast(half2v, xa1.D);                   \
    half2v x2 = __builtin_bit_cast(half2v, xa2.D);                   \
    half2v x3 = __builtin_bit_cast(half2v, xa3.D);                   \
    half2v x4 = __builtin_bit_cast(half2v, xa4.D);                   \
    half2v x5 = __builtin_bit_cast(half2v, xa5.D);                   \
    tap(x0 + w0, mx0, mn0); tap(x1 + w0, mx1, mn1);                  \
    tap(x2 + w0, mx2, mn2); tap(x3 + w0, mx3, mn3);                  \
    tap(x1 + w1, mx0, mn0); tap(x2 + w1, mx1, mn1);                  \
    tap(x3 + w1, mx2, mn2); tap(x4 + w1, mx3, mn3);                  \
    tap(x2 + w2, mx0, mn0); tap(x3 + w2, mx1, mn1);                  \
    tap(x4 + w2, mx2, mn2); tap(x5 + w2, mx3, mn3);                  \
  }
    DOD(x) DOD(y) DOD(z) DOD(w)
#undef DOD
  }

  // ---- epilogue: f32 subtract + bias; coalesced 256 B stores ----
  float bv = bias[f];
  float* ob = out + (((size_t)b * 30 + i) * 30 + j0) * 64 + f;
  if (j0 + 0 < 30) ob[0 * 64] = fmaxf((float)mx0.x, (float)mx0.y) - fminf((float)mn0.x, (float)mn0.y) + bv;
  if (j0 + 1 < 30) ob[1 * 64] = fmaxf((float)mx1.x, (float)mx1.y) - fminf((float)mn1.x, (float)mn1.y) + bv;
  if (j0 + 2 < 30) ob[2 * 64] = fmaxf((float)mx2.x, (float)mx2.y) - fminf((float)mn2.x, (float)mn2.y) + bv;
  if (j0 + 3 < 30) ob[3 * 64] = fmaxf((float)mx3.x, (float)mx3.y) - fminf((float)mn3.x, (float)mn3.y) + bv;
}

extern "C" void kernel_launch(void* const* d_in, const int* in_sizes, int n_in,
                              void* d_out, int out_size, void* d_ws, size_t ws_size,
                              hipStream_t stream) {
  const float* x = (const float*)d_in[0];
  const float* w = (const float*)d_in[1];
  const float* bias = (const float*)d_in[2];
  float* out = (float*)d_out;
  dim3 grid(30, 8);  // (row, batch) = 240 blocks, 8 waves each
  dim3 block(512);
  hipLaunchKernelGGL(trop_kernel, grid, block, 0, stream, x, w, bias, out);
}

// Round 8
// 66.616 us; speedup vs baseline: 1.4027x; 1.0014x over previous
//
#include <hip/hip_runtime.h>
#include <math.h>

// TropConv2D: out[b,i,j,f] = max_k(p[k]+w[k,f]) - min_k(p[k]+w[k,f]) + bias[f]
// k = (ki*3+kj)*32+c, 3x3 window, C=32, F=64.
// x: [8,32,32,32] f32, w: [288,64] f32, bias: [64] f32, out: [8,30,30,64] f32.
//
// R8 = R7 (packed-f16 taps 1.5 insts/tap, one-shot LDS staging, k-loop
// unroll(disable) -- the R7 spill fix) + channel-split wave pairs:
// block = 1024 = 16 waves; wave W<8 does channels 0..15, W>=8 does 16..31,
// same 4 output cols (W&7)*4... Per-wave chain halves (6 iters, 864 insts),
// 4 waves/SIMD instead of 2 -> 2x latency hiding at constant per-CU work.
// Partials merged through a 16 KB LDS buffer (1 extra barrier).

typedef _Float16 half2v __attribute__((ext_vector_type(2)));
typedef _Float16 half4v __attribute__((ext_vector_type(4)));

#define WSTRIDE 296  // halves; rows 16B-aligned

__device__ __forceinline__ void tap(half2v a, half2v& mx, half2v& mn) {
  mx = __builtin_elementwise_max(mx, a);  // v_pk_max_f16
  mn = __builtin_elementwise_min(mn, a);  // v_pk_min_f16
}

__device__ __forceinline__ half2v h2(unsigned u) {
  return __builtin_bit_cast(half2v, u);
}
__device__ __forceinline__ unsigned u32(half2v h) {
  return __builtin_bit_cast(unsigned, h);
}

__global__ __launch_bounds__(1024) void trop_kernel(
    const float* __restrict__ x, const float* __restrict__ w,
    const float* __restrict__ bias, float* __restrict__ out) {
  __shared__ _Float16 wt[64 * WSTRIDE];  // 37.9 KB: w transposed [f][kk], f16
  __shared__ _Float16 xh[3 * 32 * 32];   // 6 KB: x rows f16 [ki][col][c]
  __shared__ uint4 red[8][2][64];        // 16 KB: partial mx/mn from waves 8-15

  const int i = blockIdx.x;  // 0..29 output row
  const int b = blockIdx.y;  // 0..7 batch
  const int tid = threadIdx.x;
  const int f = tid & 63;  // lane = filter
  const int W = __builtin_amdgcn_readfirstlane(tid >> 6);  // wave 0..15
  const int j0 = (W & 7) * 4;   // wave col base
  const int chalf = W >> 3;     // channel half: 0 -> c 0..15, 1 -> c 16..31

  // ---- stage w transposed + f16: thread = (f, quad q), q covers 72 quads ----
  const int q = tid >> 6;  // 0..15
#pragma unroll
  for (int it = 0; it < 5; ++it) {
    int qq = q + it * 16;
    if (qq < 72) {
      int k0 = qq * 4;  // 0..284 step 4
      const float* wp = w + (size_t)k0 * 64 + f;
      half4v hv;
      hv.x = (_Float16)wp[0 * 64];
      hv.y = (_Float16)wp[1 * 64];
      hv.z = (_Float16)wp[2 * 64];
      hv.w = (_Float16)wp[3 * 64];
      *(half4v*)&wt[f * WSTRIDE + k0] = hv;  // 8 B aligned ds_write
    }
  }

  // ---- stage x rows i..i+2 as f16: 1536 float2 loads over 1024 threads ----
  const float* xb = x + (((size_t)b * 32 + i) * 32) * 32;
#pragma unroll
  for (int t = 0; t < 2; ++t) {
    int g = tid + t * 1024;
    if (g < 1536) {
      int ki = g >> 9;
      int rem = g & 511;
      int col = rem >> 4;
      int cp = rem & 15;
      float2 v = *(const float2*)(xb + ki * 1024 + col * 32 + cp * 2);
      half2v h;
      h.x = (_Float16)v.x;
      h.y = (_Float16)v.y;
      *(half2v*)&xh[(ki * 32 + col) * 32 + cp * 2] = h;
    }
  }

  __syncthreads();

  // clamped local columns (wave-uniform), as half offsets into a ki-row
  const int cc0 = ((j0 + 0 < 32) ? j0 + 0 : 31) * 32;
  const int cc1 = ((j0 + 1 < 32) ? j0 + 1 : 31) * 32;
  const int cc2 = ((j0 + 2 < 32) ? j0 + 2 : 31) * 32;
  const int cc3 = ((j0 + 3 < 32) ? j0 + 3 : 31) * 32;
  const int cc4 = ((j0 + 4 < 32) ? j0 + 4 : 31) * 32;
  const int cc5 = ((j0 + 5 < 32) ? j0 + 5 : 31) * 32;

  const _Float16 NI = (_Float16)(-INFINITY), PI = (_Float16)INFINITY;
  half2v mx0 = {NI, NI}, mx1 = {NI, NI}, mx2 = {NI, NI}, mx3 = {NI, NI};
  half2v mn0 = {PI, PI}, mn1 = {PI, PI}, mn2 = {PI, PI}, mn3 = {PI, PI};

#pragma clang loop unroll(disable)
  for (int kc = 0; kc < 6; ++kc) {
    const int ki = kc >> 1;                             // 0..2
    const int c8 = ((kc & 1) << 3) + (chalf << 4);      // this wave's channels
    const _Float16* xrow = &xh[ki * 1024 + c8];
    const _Float16* wrow = &wt[f * WSTRIDE + ki * 96 + c8];

    // x: 6 cols x 8 ch, wave-uniform broadcast b128
    uint4 xa0 = *(const uint4*)&xrow[cc0];
    uint4 xa1 = *(const uint4*)&xrow[cc1];
    uint4 xa2 = *(const uint4*)&xrow[cc2];
    uint4 xa3 = *(const uint4*)&xrow[cc3];
    uint4 xa4 = *(const uint4*)&xrow[cc4];
    uint4 xa5 = *(const uint4*)&xrow[cc5];
    // w: lane f's own row, 3 kj, b128 each
    uint4 wa0 = *(const uint4*)&wrow[0];
    uint4 wa1 = *(const uint4*)&wrow[32];
    uint4 wa2 = *(const uint4*)&wrow[64];

#define DOD(D)                                               \
  {                                                          \
    half2v w0 = h2(wa0.D);                                   \
    half2v w1 = h2(wa1.D);                                   \
    half2v w2 = h2(wa2.D);                                   \
    half2v x0 = h2(xa0.D);                                   \
    half2v x1 = h2(xa1.D);                                   \
    half2v x2 = h2(xa2.D);                                   \
    half2v x3 = h2(xa3.D);                                   \
    half2v x4 = h2(xa4.D);                                   \
    half2v x5 = h2(xa5.D);                                   \
    tap(x0 + w0, mx0, mn0); tap(x1 + w0, mx1, mn1);          \
    tap(x2 + w0, mx2, mn2); tap(x3 + w0, mx3, mn3);          \
    tap(x1 + w1, mx0, mn0); tap(x2 + w1, mx1, mn1);          \
    tap(x3 + w1, mx2, mn2); tap(x4 + w1, mx3, mn3);          \
    tap(x2 + w2, mx0, mn0); tap(x3 + w2, mx1, mn1);          \
    tap(x4 + w2, mx2, mn2); tap(x5 + w2, mx3, mn3);          \
  }
    DOD(x) DOD(y) DOD(z) DOD(w)
#undef DOD
  }

  // ---- cross-wave merge: waves 8-15 publish partials, waves 0-7 combine ----
  if (W >= 8) {
    uint4 pm, pn;
    pm.x = u32(mx0); pm.y = u32(mx1); pm.z = u32(mx2); pm.w = u32(mx3);
    pn.x = u32(mn0); pn.y = u32(mn1); pn.z = u32(mn2); pn.w = u32(mn3);
    red[W - 8][0][f] = pm;  // lane-consecutive b128: conflict-free
    red[W - 8][1][f] = pn;
  }
  __syncthreads();
  if (W < 8) {
    uint4 pm = red[W][0][f];
    uint4 pn = red[W][1][f];
    mx0 = __builtin_elementwise_max(mx0, h2(pm.x));
    mx1 = __builtin_elementwise_max(mx1, h2(pm.y));
    mx2 = __builtin_elementwise_max(mx2, h2(pm.z));
    mx3 = __builtin_elementwise_max(mx3, h2(pm.w));
    mn0 = __builtin_elementwise_min(mn0, h2(pn.x));
    mn1 = __builtin_elementwise_min(mn1, h2(pn.y));
    mn2 = __builtin_elementwise_min(mn2, h2(pn.z));
    mn3 = __builtin_elementwise_min(mn3, h2(pn.w));

    // ---- epilogue: f32 subtract + bias; coalesced 256 B stores ----
    float bv = bias[f];
    float* ob = out + (((size_t)b * 30 + i) * 30 + j0) * 64 + f;
    if (j0 + 0 < 30) ob[0 * 64] = fmaxf((float)mx0.x, (float)mx0.y) - fminf((float)mn0.x, (float)mn0.y) + bv;
    if (j0 + 1 < 30) ob[1 * 64] = fmaxf((float)mx1.x, (float)mx1.y) - fminf((float)mn1.x, (float)mn1.y) + bv;
    if (j0 + 2 < 30) ob[2 * 64] = fmaxf((float)mx2.x, (float)mx2.y) - fminf((float)mn2.x, (float)mn2.y) + bv;
    if (j0 + 3 < 30) ob[3 * 64] = fmaxf((float)mx3.x, (float)mx3.y) - fminf((float)mn3.x, (float)mn3.y) + bv;
  }
}

extern "C" void kernel_launch(void* const* d_in, const int* in_sizes, int n_in,
                              void* d_out, int out_size, void* d_ws, size_t ws_size,
                              hipStream_t stream) {
  const float* x = (const float*)d_in[0];
  const float* w = (const float*)d_in[1];
  const float* bias = (const float*)d_in[2];
  float* out = (float*)d_out;
  dim3 grid(30, 8);   // (row, batch) = 240 blocks, 16 waves each
  dim3 block(1024);
  hipLaunchKernelGGL(trop_kernel, grid, block, 0, stream, x, w, bias, out);
}